// Round 4
// baseline (1277.985 us; speedup 1.0000x reference)
//
#include <hip/hip_runtime.h>
#include <hip/hip_bf16.h>

#define LYR 6
#define H 768
#define NH 12
#define HD 64
#define FF 3072
#define T 512
#define BB 4
#define M_TOK 2048
#define SCALE 0.125f

typedef __hip_bfloat16 bf16;
typedef __hip_bfloat162 bf16x2;
typedef __attribute__((ext_vector_type(8))) short short8;
typedef __attribute__((ext_vector_type(4))) float f32x4;

// ---------------- block reduction helpers (256 threads) ----------------
__device__ __forceinline__ float block_sum256(float v) {
    __shared__ float sm[4];
    #pragma unroll
    for (int o = 32; o > 0; o >>= 1) v += __shfl_down(v, o);
    if ((threadIdx.x & 63) == 0) sm[threadIdx.x >> 6] = v;
    __syncthreads();
    float r = sm[0] + sm[1] + sm[2] + sm[3];
    __syncthreads();
    return r;
}

// async global->LDS, 16 B per lane; lds base must be wave-uniform
__device__ __forceinline__ void gload_lds16(const bf16* g, bf16* l) {
    __builtin_amdgcn_global_load_lds(
        (const __attribute__((address_space(1))) void*)g,
        (__attribute__((address_space(3))) void*)l, 16, 0, 0);
}

// ---------------- GEMM core: C[128 x NT*32] = A(128,K) * Bt(NT*32,K)^T ----
template<int NT>
__device__ __forceinline__ void gemm_core(
    const bf16* __restrict__ A, int lda,
    const bf16* __restrict__ Bt, int ldb,
    int K, f32x4 acc[4][NT])
{
    constexpr int BN = NT * 32;
    __shared__ bf16 sA[128 * 32];
    __shared__ bf16 sB[BN * 32];
    const int tid = threadIdx.x;
    const int wave = tid >> 6, lane = tid & 63;
    const int wr = wave >> 1, wc = wave & 1;
    const int quad = lane >> 4, m16 = lane & 15;

    for (int k0 = 0; k0 < K; k0 += 32) {
        #pragma unroll
        for (int i = 0; i < 2; i++) {
            int c = tid + i * 256; int r = c >> 2, k8 = c & 3;
            gload_lds16(A + (size_t)r * lda + k0 + k8 * 8,
                        sA + (i * 256 + wave * 64) * 8);
        }
        #pragma unroll
        for (int i = 0; i < BN / 64; i++) {
            int c = tid + i * 256; int r = c >> 2, k8 = c & 3;
            gload_lds16(Bt + (size_t)r * ldb + k0 + k8 * 8,
                        sB + (i * 256 + wave * 64) * 8);
        }
        __syncthreads();
        short8 af[4], bfr[NT];
        #pragma unroll
        for (int mt = 0; mt < 4; mt++) {
            int row = wr * 64 + mt * 16 + m16;
            af[mt] = *(const short8*)(sA + row * 32 + quad * 8);
        }
        #pragma unroll
        for (int nt = 0; nt < NT; nt++) {
            int row = wc * NT * 16 + nt * 16 + m16;
            bfr[nt] = *(const short8*)(sB + row * 32 + quad * 8);
        }
        #pragma unroll
        for (int mt = 0; mt < 4; mt++)
            #pragma unroll
            for (int nt = 0; nt < NT; nt++)
                acc[mt][nt] = __builtin_amdgcn_mfma_f32_16x16x32_bf16(
                    af[mt], bfr[nt], acc[mt][nt], 0, 0, 0);
        __syncthreads();
    }
}

#define EPI_IDX() \
    const int tid = threadIdx.x; \
    const int wave = tid >> 6, lane = tid & 63; \
    const int wr = wave >> 1, wc = wave & 1; \
    const int quad = lane >> 4, m16 = lane & 15;

// ---------------- weight transpose + convert, 64x64 tile, vectorized ----
// src (R,C) f32 -> dst (C,R) bf16
__global__ __launch_bounds__(256) void k_transpose(
    const float* __restrict__ src, bf16* __restrict__ dst, int R, int C)
{
    __shared__ float tile[64][65];
    const int l = blockIdx.z;
    src += (size_t)l * R * C;
    dst += (size_t)l * R * C;
    const int c0 = blockIdx.x * 64, r0 = blockIdx.y * 64;
    // load: thread -> 4 rows x float4
    const int c4 = (threadIdx.x & 15) * 4, rr = threadIdx.x >> 4;
    #pragma unroll
    for (int i = 0; i < 4; i++) {
        int r = rr + i * 16;
        float4 v = *(const float4*)(src + (size_t)(r0 + r) * C + c0 + c4);
        tile[r][c4] = v.x; tile[r][c4 + 1] = v.y;
        tile[r][c4 + 2] = v.z; tile[r][c4 + 3] = v.w;
    }
    __syncthreads();
    // store: thread -> 2 dst rows x uint4 (8 bf16 = 8 consecutive r)
    const int r8 = (threadIdx.x & 7) * 8, cc = threadIdx.x >> 3;
    #pragma unroll
    for (int i = 0; i < 2; i++) {
        int c = cc + i * 32;
        bf16 tmp[8];
        #pragma unroll
        for (int j = 0; j < 8; j++) tmp[j] = __float2bfloat16(tile[r8 + j][c]);
        *(uint4*)(dst + (size_t)(c0 + c) * R + r0 + r8) = *(uint4*)tmp;
    }
}

// ---------------- precompute packed bias/decay once ---------------------
// BD[idx] = (x = dead ? -inf : abias*decay, y = decay) bf16x2
// grid (T/8, B*NH); thread: 16 consecutive s of one t-row
__global__ __launch_bounds__(256) void k_prep(
    const float* __restrict__ abias, const float* __restrict__ decay,
    const int* __restrict__ am, bf16x2* __restrict__ BD)
{
    __shared__ int ams[T];
    const int n = blockIdx.y, b = n / NH;
    for (int s = threadIdx.x; s < T; s += 256) ams[s] = am[b * T + s];
    __syncthreads();
    const int t = blockIdx.x * 8 + (threadIdx.x >> 5);
    const int s0 = (threadIdx.x & 31) * 16;
    const bool amt = ams[t] != 0;
    const size_t base = ((size_t)n * T + t) * T;
    const float4* ab4 = (const float4*)(abias + base + s0);
    const float4* de4 = (const float4*)(decay + base + s0);
    bf16x2 out[16];
    #pragma unroll
    for (int g = 0; g < 4; g++) {
        float4 a = ab4[g], d = de4[g];
        float av[4] = {a.x, a.y, a.z, a.w}, dv[4] = {d.x, d.y, d.z, d.w};
        #pragma unroll
        for (int j = 0; j < 4; j++) {
            int s = s0 + g * 4 + j;
            bool dead = (!(amt && (ams[s] != 0))) || (t >= 1 && s == 0);
            bf16x2 o;
            o.x = __float2bfloat16(dead ? -__builtin_inff() : av[j] * dv[j]);
            o.y = __float2bfloat16(dv[j]);
            out[g * 4 + j] = o;
        }
    }
    #pragma unroll
    for (int g = 0; g < 4; g++)
        *(uint4*)((unsigned int*)BD + base + s0 + g * 4) = *(uint4*)(out + g * 4);
}

// ---------------- layernorm: x (2048,768) f32 -> out bf16 --------------
__global__ __launch_bounds__(256) void k_ln(
    const float* __restrict__ x, const float* __restrict__ g,
    const float* __restrict__ b, bf16* __restrict__ out)
{
    const int row = blockIdx.x;
    const float* xr = x + (size_t)row * H;
    const int tid = threadIdx.x;
    float v0 = xr[tid], v1 = xr[tid + 256], v2 = xr[tid + 512];
    float mean = block_sum256(v0 + v1 + v2) * (1.0f / H);
    float d0 = v0 - mean, d1 = v1 - mean, d2 = v2 - mean;
    float var = block_sum256(d0 * d0 + d1 * d1 + d2 * d2) * (1.0f / H);
    float rs = rsqrtf(var + 1e-5f);
    bf16* orow = out + (size_t)row * H;
    orow[tid]       = __float2bfloat16(d0 * rs * g[tid]       + b[tid]);
    orow[tid + 256] = __float2bfloat16(d1 * rs * g[tid + 256] + b[tid + 256]);
    orow[tid + 512] = __float2bfloat16(d2 * rs * g[tid + 512] + b[tid + 512]);
}

// ---------------- fused QKV GEMM ---------------------------------------
__global__ __launch_bounds__(256, 2) void k_qkv(
    const bf16* __restrict__ h,
    const bf16* __restrict__ Wqt, const bf16* __restrict__ Wkt, const bf16* __restrict__ Wvt,
    const float* __restrict__ bq, const float* __restrict__ bk, const float* __restrict__ bv,
    bf16* __restrict__ qb, bf16* __restrict__ kb, bf16* __restrict__ vtb)
{
    const int bm = blockIdx.x, bc = blockIdx.y;
    const int mat = bc / 6, nc = (bc % 6) * 128;
    const bf16* Bt = (mat == 0 ? Wqt : (mat == 1 ? Wkt : Wvt)) + (size_t)nc * H;
    const float* bias = (mat == 0 ? bq : (mat == 1 ? bk : bv));
    f32x4 acc[4][4];
    for (int a = 0; a < 4; a++) for (int bb = 0; bb < 4; bb++)
        for (int i = 0; i < 4; i++) acc[a][bb][i] = 0.0f;
    gemm_core<4>(h + (size_t)bm * 128 * H, H, Bt, H, H, acc);
    EPI_IDX();
    #pragma unroll
    for (int mt = 0; mt < 4; mt++)
        #pragma unroll
        for (int nt = 0; nt < 4; nt++)
            #pragma unroll
            for (int i = 0; i < 4; i++) {
                int r = bm * 128 + wr * 64 + mt * 16 + quad * 4 + i;
                int c = nc + wc * 64 + nt * 16 + m16;
                float v = acc[mt][nt][i] + bias[c];
                int t = r >> 2, b = r & 3, hh = c >> 6, d = c & 63;
                int n = b * NH + hh;
                if (mat == 0)
                    qb[((size_t)(n * T + t)) * HD + d] = __float2bfloat16(v * SCALE);
                else if (mat == 1)
                    kb[((size_t)(n * T + t)) * HD + d] = __float2bfloat16(v);
                else
                    vtb[((size_t)(n * HD + d)) * T + t] = __float2bfloat16(v);
            }
}

// ---------------- fused flash attention: scores+softmax+PV --------------
// grid (T/64, B*NH).  Wave w owns q rows [w*16, w*16+16).
__global__ __launch_bounds__(256, 2) void k_attn(
    const bf16* __restrict__ qb, const bf16* __restrict__ kb,
    const bf16* __restrict__ vtb, const bf16x2* __restrict__ BD,
    bf16* __restrict__ ab)
{
    __shared__ bf16 Qs[64][72];
    __shared__ bf16 Ks[128][72];
    __shared__ bf16 Vs[64][136];
    __shared__ bf16 Ps[4][16][136];
    const int n = blockIdx.y, q0 = blockIdx.x * 64;
    const int tid = threadIdx.x, wave = tid >> 6, lane = tid & 63;
    const int quad = lane >> 4, m16 = lane & 15;

    #pragma unroll
    for (int it = 0; it < 2; it++) {
        int c = it * 256 + tid, r = c >> 3, c8 = c & 7;
        *(uint4*)&Qs[r][c8 * 8] =
            *(const uint4*)(qb + ((size_t)n * T + q0 + r) * HD + c8 * 8);
    }

    f32x4 oacc[4];
    float m_i[4], l_i[4];
    #pragma unroll
    for (int i = 0; i < 4; i++) { m_i[i] = -__builtin_inff(); l_i[i] = 0.0f; }
    #pragma unroll
    for (int dt = 0; dt < 4; dt++)
        #pragma unroll
        for (int i = 0; i < 4; i++) oacc[dt][i] = 0.0f;
    __syncthreads();

    for (int st = 0; st < 4; st++) {
        #pragma unroll
        for (int it = 0; it < 4; it++) {
            int c = it * 256 + tid, r = c >> 3, c8 = c & 7;
            *(uint4*)&Ks[r][c8 * 8] =
                *(const uint4*)(kb + ((size_t)n * T + st * 128 + r) * HD + c8 * 8);
        }
        #pragma unroll
        for (int it = 0; it < 4; it++) {
            int c = it * 256 + tid, d = c >> 4, s8 = c & 15;
            *(uint4*)&Vs[d][s8 * 8] =
                *(const uint4*)(vtb + ((size_t)n * HD + d) * T + st * 128 + s8 * 8);
        }
        __syncthreads();

        f32x4 sacc[8];
        #pragma unroll
        for (int ct = 0; ct < 8; ct++)
            #pragma unroll
            for (int i = 0; i < 4; i++) sacc[ct][i] = 0.0f;
        #pragma unroll
        for (int ks = 0; ks < 2; ks++) {
            short8 af = *(const short8*)&Qs[wave * 16 + m16][ks * 32 + quad * 8];
            #pragma unroll
            for (int ct = 0; ct < 8; ct++) {
                short8 bfr = *(const short8*)&Ks[ct * 16 + m16][ks * 32 + quad * 8];
                sacc[ct] = __builtin_amdgcn_mfma_f32_16x16x32_bf16(af, bfr, sacc[ct], 0, 0, 0);
            }
        }

        // epilogue: val = qk * D + B  (packed BD, C layout: col=m16, row=quad*4+i)
        const int trow = q0 + wave * 16 + quad * 4;
        float val[8][4];
        #pragma unroll
        for (int ct = 0; ct < 8; ct++) {
            int s = st * 128 + ct * 16 + m16;
            #pragma unroll
            for (int i = 0; i < 4; i++) {
                size_t idx = ((size_t)n * T + trow + i) * T + s;
                bf16x2 bd = BD[idx];
                val[ct][i] = sacc[ct][i] * __bfloat162float(bd.y)
                           + __bfloat162float(bd.x);
            }
        }

        float alpha[4], mn[4];
        #pragma unroll
        for (int i = 0; i < 4; i++) {
            float rm = val[0][i];
            #pragma unroll
            for (int ct = 1; ct < 8; ct++) rm = fmaxf(rm, val[ct][i]);
            #pragma unroll
            for (int o = 8; o > 0; o >>= 1) rm = fmaxf(rm, __shfl_xor(rm, o));
            mn[i] = fmaxf(m_i[i], rm);
            alpha[i] = __expf(m_i[i] - mn[i]);
            m_i[i] = mn[i];
        }
        float rs[4] = {0.0f, 0.0f, 0.0f, 0.0f};
        #pragma unroll
        for (int ct = 0; ct < 8; ct++) {
            #pragma unroll
            for (int i = 0; i < 4; i++) {
                float pv = __expf(val[ct][i] - mn[i]);
                rs[i] += pv;
                Ps[wave][quad * 4 + i][ct * 16 + m16] = __float2bfloat16(pv);
            }
        }
        #pragma unroll
        for (int i = 0; i < 4; i++) {
            #pragma unroll
            for (int o = 8; o > 0; o >>= 1) rs[i] += __shfl_xor(rs[i], o);
            l_i[i] = l_i[i] * alpha[i] + rs[i];
        }
        #pragma unroll
        for (int dt = 0; dt < 4; dt++)
            #pragma unroll
            for (int i = 0; i < 4; i++) oacc[dt][i] *= alpha[i];

        #pragma unroll
        for (int ks = 0; ks < 4; ks++) {
            short8 af = *(const short8*)&Ps[wave][m16][ks * 32 + quad * 8];
            #pragma unroll
            for (int dt = 0; dt < 4; dt++) {
                short8 bfr = *(const short8*)&Vs[dt * 16 + m16][ks * 32 + quad * 8];
                oacc[dt] = __builtin_amdgcn_mfma_f32_16x16x32_bf16(af, bfr, oacc[dt], 0, 0, 0);
            }
        }
        __syncthreads();
    }

    const int b = n / NH, hh = n % NH;
    #pragma unroll
    for (int i = 0; i < 4; i++) {
        int t = q0 + wave * 16 + quad * 4 + i;
        float inv = 1.0f / l_i[i];
        #pragma unroll
        for (int dt = 0; dt < 4; dt++) {
            int d = dt * 16 + m16;
            ab[((size_t)(t * BB + b)) * H + hh * HD + d] =
                __float2bfloat16(oacc[dt][i] * inv);
        }
    }
}

// ---------------- attn out proj + residual, split-K=2, atomic epilogue --
__global__ __launch_bounds__(256, 2) void k_out(
    const bf16* __restrict__ ab, const bf16* __restrict__ Wot,
    const float* __restrict__ bo, float* __restrict__ x)
{
    const int bm = blockIdx.x, bn = blockIdx.y, kc = blockIdx.z;
    f32x4 acc[4][4];
    for (int a = 0; a < 4; a++) for (int bb = 0; bb < 4; bb++)
        for (int i = 0; i < 4; i++) acc[a][bb][i] = 0.0f;
    gemm_core<4>(ab + (size_t)bm * 128 * H + kc * 384, H,
                 Wot + (size_t)bn * 128 * H + kc * 384, H, 384, acc);
    EPI_IDX();
    #pragma unroll
    for (int mt = 0; mt < 4; mt++)
        #pragma unroll
        for (int nt = 0; nt < 4; nt++)
            #pragma unroll
            for (int i = 0; i < 4; i++) {
                int r = bm * 128 + wr * 64 + mt * 16 + quad * 4 + i;
                int c = bn * 128 + wc * 64 + nt * 16 + m16;
                size_t idx = (size_t)r * H + c;
                float v = acc[mt][nt][i] + (kc == 0 ? bo[c] : 0.0f);
                atomicAdd(&x[idx], v);
            }
}

// ---------------- FFN1 + gelu -------------------------------------------
__global__ __launch_bounds__(256, 2) void k_ffn1(
    const bf16* __restrict__ h, const bf16* __restrict__ W1t,
    const float* __restrict__ b1, bf16* __restrict__ gb)
{
    const int bm = blockIdx.x, bn = blockIdx.y;
    f32x4 acc[4][4];
    for (int a = 0; a < 4; a++) for (int bb = 0; bb < 4; bb++)
        for (int i = 0; i < 4; i++) acc[a][bb][i] = 0.0f;
    gemm_core<4>(h + (size_t)bm * 128 * H, H, W1t + (size_t)bn * 128 * H, H, H, acc);
    EPI_IDX();
    #pragma unroll
    for (int mt = 0; mt < 4; mt++)
        #pragma unroll
        for (int nt = 0; nt < 4; nt++)
            #pragma unroll
            for (int i = 0; i < 4; i++) {
                int r = bm * 128 + wr * 64 + mt * 16 + quad * 4 + i;
                int c = bn * 128 + wc * 64 + nt * 16 + m16;
                float u = acc[mt][nt][i] + b1[c];
                float gl = 0.5f * u * (1.0f + tanhf(0.7978845608028654f * (u + 0.044715f * u * u * u)));
                gb[(size_t)r * FF + c] = __float2bfloat16(gl);
            }
}

// ---------------- FFN2 + residual, split-K=4, atomic epilogue -----------
__global__ __launch_bounds__(256, 2) void k_ffn2(
    const bf16* __restrict__ gb, const bf16* __restrict__ W2t,
    const float* __restrict__ b2, float* __restrict__ x)
{
    const int bm = blockIdx.x, bn = blockIdx.y, kc = blockIdx.z;
    f32x4 acc[4][4];
    for (int a = 0; a < 4; a++) for (int bb = 0; bb < 4; bb++)
        for (int i = 0; i < 4; i++) acc[a][bb][i] = 0.0f;
    gemm_core<4>(gb + (size_t)bm * 128 * FF + kc * 768, FF,
                 W2t + (size_t)bn * 128 * FF + kc * 768, FF, 768, acc);
    EPI_IDX();
    #pragma unroll
    for (int mt = 0; mt < 4; mt++)
        #pragma unroll
        for (int nt = 0; nt < 4; nt++)
            #pragma unroll
            for (int i = 0; i < 4; i++) {
                int r = bm * 128 + wr * 64 + mt * 16 + quad * 4 + i;
                int c = bn * 128 + wc * 64 + nt * 16 + m16;
                size_t idx = (size_t)r * H + c;
                float v = acc[mt][nt][i] + (kc == 0 ? b2[c] : 0.0f);
                atomicAdd(&x[idx], v);
            }
}

// ---------------- host ---------------------------------------------------
extern "C" void kernel_launch(void* const* d_in, const int* in_sizes, int n_in,
                              void* d_out, int out_size, void* d_ws, size_t ws_size,
                              hipStream_t stream) {
    const float* x_in  = (const float*)d_in[0];
    const float* abias = (const float*)d_in[1];
    const float* decay = (const float*)d_in[2];
    const int*   am    = (const int*)d_in[3];
    const float* Wq = (const float*)d_in[4];
    const float* bq = (const float*)d_in[5];
    const float* Wk = (const float*)d_in[6];
    const float* bk = (const float*)d_in[7];
    const float* Wv = (const float*)d_in[8];
    const float* bv = (const float*)d_in[9];
    const float* Wo = (const float*)d_in[10];
    const float* bo = (const float*)d_in[11];
    const float* ln1g = (const float*)d_in[12];
    const float* ln1b = (const float*)d_in[13];
    const float* ln2g = (const float*)d_in[14];
    const float* ln2b = (const float*)d_in[15];
    const float* W1 = (const float*)d_in[16];
    const float* b1 = (const float*)d_in[17];
    const float* W2 = (const float*)d_in[18];
    const float* b2 = (const float*)d_in[19];
    float* x = (float*)d_out;

    char* p = (char*)d_ws;
    auto alloc = [&](size_t bytes) {
        char* r = p;
        p += (bytes + 255) & ~(size_t)255;
        return r;
    };
    bf16* Wqt = (bf16*)alloc((size_t)LYR * H * H * 2);
    bf16* Wkt = (bf16*)alloc((size_t)LYR * H * H * 2);
    bf16* Wvt = (bf16*)alloc((size_t)LYR * H * H * 2);
    bf16* Wot = (bf16*)alloc((size_t)LYR * H * H * 2);
    bf16* W1t = (bf16*)alloc((size_t)LYR * H * FF * 2);
    bf16* W2t = (bf16*)alloc((size_t)LYR * H * FF * 2);
    bf16* hbuf = (bf16*)alloc((size_t)M_TOK * H * 2);
    bf16* qb   = (bf16*)alloc((size_t)BB * NH * T * HD * 2);
    bf16* kb   = (bf16*)alloc((size_t)BB * NH * T * HD * 2);
    bf16* vtb  = (bf16*)alloc((size_t)BB * NH * T * HD * 2);
    bf16* ab   = (bf16*)alloc((size_t)BB * NH * T * HD * 2);
    bf16x2* BD = (bf16x2*)alloc((size_t)BB * NH * T * T * 4);
    bf16* gb   = (bf16*)alloc((size_t)M_TOK * FF * 2);

    hipMemcpyAsync(x, x_in, (size_t)M_TOK * H * 4, hipMemcpyDeviceToDevice, stream);

    dim3 blk(256);
    k_prep<<<dim3(T / 8, BB * NH), blk, 0, stream>>>(abias, decay, am, BD);
    k_transpose<<<dim3(H / 64, H / 64, LYR), blk, 0, stream>>>(Wq, Wqt, H, H);
    k_transpose<<<dim3(H / 64, H / 64, LYR), blk, 0, stream>>>(Wk, Wkt, H, H);
    k_transpose<<<dim3(H / 64, H / 64, LYR), blk, 0, stream>>>(Wv, Wvt, H, H);
    k_transpose<<<dim3(H / 64, H / 64, LYR), blk, 0, stream>>>(Wo, Wot, H, H);
    k_transpose<<<dim3(FF / 64, H / 64, LYR), blk, 0, stream>>>(W1, W1t, H, FF);
    k_transpose<<<dim3(H / 64, FF / 64, LYR), blk, 0, stream>>>(W2, W2t, FF, H);

    for (int l = 0; l < LYR; l++) {
        size_t wo = (size_t)l * H * H;
        size_t wf = (size_t)l * H * FF;
        k_ln<<<dim3(M_TOK), blk, 0, stream>>>(x, ln1g + l * H, ln1b + l * H, hbuf);
        k_qkv<<<dim3(16, 18), blk, 0, stream>>>(hbuf, Wqt + wo, Wkt + wo, Wvt + wo,
                                                bq + l * H, bk + l * H, bv + l * H,
                                                qb, kb, vtb);
        k_attn<<<dim3(T / 64, BB * NH), blk, 0, stream>>>(qb, kb, vtb, BD, ab);
        k_out<<<dim3(16, 6, 2), blk, 0, stream>>>(ab, Wot + wo, bo + l * H, x);
        k_ln<<<dim3(M_TOK), blk, 0, stream>>>(x, ln2g + l * H, ln2b + l * H, hbuf);
        k_ffn1<<<dim3(16, 24), blk, 0, stream>>>(hbuf, W1t + wf, b1 + l * FF, gb);
        k_ffn2<<<dim3(16, 6, 4), blk, 0, stream>>>(gb, W2t + wf, b2 + l * H, x);
    }
}

// Round 5
// 1254.247 us; speedup vs baseline: 1.0189x; 1.0189x over previous
//
#include <hip/hip_runtime.h>
#include <hip/hip_bf16.h>

#define LYR 6
#define H 768
#define NH 12
#define HD 64
#define FF 3072
#define T 512
#define BB 4
#define M_TOK 2048
#define SCALE 0.125f

typedef __hip_bfloat16 bf16;
typedef __hip_bfloat162 bf16x2;
typedef __attribute__((ext_vector_type(8))) short short8;
typedef __attribute__((ext_vector_type(4))) float f32x4;

// ---------------- block reduction helpers (256 threads) ----------------
__device__ __forceinline__ float block_sum256(float v) {
    __shared__ float sm[4];
    #pragma unroll
    for (int o = 32; o > 0; o >>= 1) v += __shfl_down(v, o);
    if ((threadIdx.x & 63) == 0) sm[threadIdx.x >> 6] = v;
    __syncthreads();
    float r = sm[0] + sm[1] + sm[2] + sm[3];
    __syncthreads();
    return r;
}

// async global->LDS, 16 B per lane; lds base must be wave-uniform
__device__ __forceinline__ void gload_lds16(const bf16* g, bf16* l) {
    __builtin_amdgcn_global_load_lds(
        (const __attribute__((address_space(1))) void*)g,
        (__attribute__((address_space(3))) void*)l, 16, 0, 0);
}

// ---------------- GEMM core: C[128 x NT*32] = A(128,K) * Bt(NT*32,K)^T ----
template<int NT>
__device__ __forceinline__ void gemm_core(
    const bf16* __restrict__ A, int lda,
    const bf16* __restrict__ Bt, int ldb,
    int K, f32x4 acc[4][NT])
{
    constexpr int BN = NT * 32;
    __shared__ bf16 sA[128 * 32];
    __shared__ bf16 sB[BN * 32];
    const int tid = threadIdx.x;
    const int wave = tid >> 6, lane = tid & 63;
    const int wr = wave >> 1, wc = wave & 1;
    const int quad = lane >> 4, m16 = lane & 15;

    for (int k0 = 0; k0 < K; k0 += 32) {
        #pragma unroll
        for (int i = 0; i < 2; i++) {
            int c = tid + i * 256; int r = c >> 2, k8 = c & 3;
            gload_lds16(A + (size_t)r * lda + k0 + k8 * 8,
                        sA + (i * 256 + wave * 64) * 8);
        }
        #pragma unroll
        for (int i = 0; i < BN / 64; i++) {
            int c = tid + i * 256; int r = c >> 2, k8 = c & 3;
            gload_lds16(Bt + (size_t)r * ldb + k0 + k8 * 8,
                        sB + (i * 256 + wave * 64) * 8);
        }
        __syncthreads();
        short8 af[4], bfr[NT];
        #pragma unroll
        for (int mt = 0; mt < 4; mt++) {
            int row = wr * 64 + mt * 16 + m16;
            af[mt] = *(const short8*)(sA + row * 32 + quad * 8);
        }
        #pragma unroll
        for (int nt = 0; nt < NT; nt++) {
            int row = wc * NT * 16 + nt * 16 + m16;
            bfr[nt] = *(const short8*)(sB + row * 32 + quad * 8);
        }
        #pragma unroll
        for (int mt = 0; mt < 4; mt++)
            #pragma unroll
            for (int nt = 0; nt < NT; nt++)
                acc[mt][nt] = __builtin_amdgcn_mfma_f32_16x16x32_bf16(
                    af[mt], bfr[nt], acc[mt][nt], 0, 0, 0);
        __syncthreads();
    }
}

#define EPI_IDX() \
    const int tid = threadIdx.x; \
    const int wave = tid >> 6, lane = tid & 63; \
    const int wr = wave >> 1, wc = wave & 1; \
    const int quad = lane >> 4, m16 = lane & 15;

// ---------------- weight transpose + convert, 64x64 tile, vectorized ----
// src (R,C) f32 -> dst (C,R) bf16
__global__ __launch_bounds__(256) void k_transpose(
    const float* __restrict__ src, bf16* __restrict__ dst, int R, int C)
{
    __shared__ float tile[64][65];
    const int l = blockIdx.z;
    src += (size_t)l * R * C;
    dst += (size_t)l * R * C;
    const int c0 = blockIdx.x * 64, r0 = blockIdx.y * 64;
    const int c4 = (threadIdx.x & 15) * 4, rr = threadIdx.x >> 4;
    #pragma unroll
    for (int i = 0; i < 4; i++) {
        int r = rr + i * 16;
        float4 v = *(const float4*)(src + (size_t)(r0 + r) * C + c0 + c4);
        tile[r][c4] = v.x; tile[r][c4 + 1] = v.y;
        tile[r][c4 + 2] = v.z; tile[r][c4 + 3] = v.w;
    }
    __syncthreads();
    const int r8 = (threadIdx.x & 7) * 8, cc = threadIdx.x >> 3;
    #pragma unroll
    for (int i = 0; i < 2; i++) {
        int c = cc + i * 32;
        bf16 tmp[8];
        #pragma unroll
        for (int j = 0; j < 8; j++) tmp[j] = __float2bfloat16(tile[r8 + j][c]);
        *(uint4*)(dst + (size_t)(c0 + c) * R + r0 + r8) = *(uint4*)tmp;
    }
}

// ---------------- precompute packed bias/decay once (swizzled layout) ---
// BD element (bf16x2): .x = dead ? -inf : abias*decay ; .y = decay
// layout: flat = ((n*4+st)*128 + tg)*512 + s_local*4 + ti
//   where tg = t>>2, ti = t&3, st = s>>7, s_local = s&127
// grid (T/16, 4, B*NH); thread: s_local = tid&127, tg half = tid>>7
__global__ __launch_bounds__(256) void k_prep(
    const float* __restrict__ abias, const float* __restrict__ decay,
    const int* __restrict__ am, bf16x2* __restrict__ BD)
{
    const int n = blockIdx.z, st = blockIdx.y, b = n / NH;
    const int sl = threadIdx.x & 127;
    const int s = st * 128 + sl;
    const int tg0 = blockIdx.x * 4 + (threadIdx.x >> 7);
    const bool ams = am[b * T + s] != 0;
    #pragma unroll
    for (int it = 0; it < 2; it++) {
        int tg = tg0 + it * 2;
        bf16x2 o[4];
        #pragma unroll
        for (int ti = 0; ti < 4; ti++) {
            int t = tg * 4 + ti;
            size_t src = ((size_t)n * T + t) * T + s;
            float de = decay[src];
            float av = abias[src];
            bool dead = (!((am[b * T + t] != 0) && ams)) || (t >= 1 && s == 0);
            o[ti].x = __float2bfloat16(dead ? -__builtin_inff() : av * de);
            o[ti].y = __float2bfloat16(de);
        }
        size_t dst = (((size_t)(n * 4 + st) * 128 + tg) * 512) + sl * 4;
        *(uint4*)(BD + dst) = *(uint4*)o;
    }
}

// ---------------- layernorm: x (2048,768) f32 -> out bf16 --------------
__global__ __launch_bounds__(256) void k_ln(
    const float* __restrict__ x, const float* __restrict__ g,
    const float* __restrict__ b, bf16* __restrict__ out)
{
    const int row = blockIdx.x;
    const float* xr = x + (size_t)row * H;
    const int tid = threadIdx.x;
    float v0 = xr[tid], v1 = xr[tid + 256], v2 = xr[tid + 512];
    float mean = block_sum256(v0 + v1 + v2) * (1.0f / H);
    float d0 = v0 - mean, d1 = v1 - mean, d2 = v2 - mean;
    float var = block_sum256(d0 * d0 + d1 * d1 + d2 * d2) * (1.0f / H);
    float rs = rsqrtf(var + 1e-5f);
    bf16* orow = out + (size_t)row * H;
    orow[tid]       = __float2bfloat16(d0 * rs * g[tid]       + b[tid]);
    orow[tid + 256] = __float2bfloat16(d1 * rs * g[tid + 256] + b[tid + 256]);
    orow[tid + 512] = __float2bfloat16(d2 * rs * g[tid + 512] + b[tid + 512]);
}

// ---------------- fused QKV GEMM ---------------------------------------
__global__ __launch_bounds__(256, 2) void k_qkv(
    const bf16* __restrict__ h,
    const bf16* __restrict__ Wqt, const bf16* __restrict__ Wkt, const bf16* __restrict__ Wvt,
    const float* __restrict__ bq, const float* __restrict__ bk, const float* __restrict__ bv,
    bf16* __restrict__ qb, bf16* __restrict__ kb, bf16* __restrict__ vtb)
{
    const int bm = blockIdx.x, bc = blockIdx.y;
    const int mat = bc / 6, nc = (bc % 6) * 128;
    const bf16* Bt = (mat == 0 ? Wqt : (mat == 1 ? Wkt : Wvt)) + (size_t)nc * H;
    const float* bias = (mat == 0 ? bq : (mat == 1 ? bk : bv));
    f32x4 acc[4][4];
    for (int a = 0; a < 4; a++) for (int bb = 0; bb < 4; bb++)
        for (int i = 0; i < 4; i++) acc[a][bb][i] = 0.0f;
    gemm_core<4>(h + (size_t)bm * 128 * H, H, Bt, H, H, acc);
    EPI_IDX();
    #pragma unroll
    for (int mt = 0; mt < 4; mt++)
        #pragma unroll
        for (int nt = 0; nt < 4; nt++)
            #pragma unroll
            for (int i = 0; i < 4; i++) {
                int r = bm * 128 + wr * 64 + mt * 16 + quad * 4 + i;
                int c = nc + wc * 64 + nt * 16 + m16;
                float v = acc[mt][nt][i] + bias[c];
                int t = r >> 2, b = r & 3, hh = c >> 6, d = c & 63;
                int n = b * NH + hh;
                if (mat == 0)
                    qb[((size_t)(n * T + t)) * HD + d] = __float2bfloat16(v * SCALE);
                else if (mat == 1)
                    kb[((size_t)(n * T + t)) * HD + d] = __float2bfloat16(v);
                else
                    vtb[((size_t)(n * HD + d)) * T + t] = __float2bfloat16(v);
            }
}

// ---------------- fused flash attention: scores+softmax+PV --------------
// grid (T/64, B*NH).  Wave w owns q rows [w*16, w*16+16).
__global__ __launch_bounds__(256, 2) void k_attn(
    const bf16* __restrict__ qb, const bf16* __restrict__ kb,
    const bf16* __restrict__ vtb, const bf16x2* __restrict__ BD,
    bf16* __restrict__ ab)
{
    __shared__ bf16 Qs[64][72];
    __shared__ bf16 Ks[128][72];
    __shared__ bf16 Vs[64][136];
    __shared__ bf16 Ps[4][16][136];
    const int n = blockIdx.y, q0 = blockIdx.x * 64;
    const int tid = threadIdx.x, wave = tid >> 6, lane = tid & 63;
    const int quad = lane >> 4, m16 = lane & 15;

    #pragma unroll
    for (int it = 0; it < 2; it++) {
        int c = it * 256 + tid, r = c >> 3, c8 = c & 7;
        *(uint4*)&Qs[r][c8 * 8] =
            *(const uint4*)(qb + ((size_t)n * T + q0 + r) * HD + c8 * 8);
    }

    f32x4 oacc[4];
    float m_i[4], l_i[4];
    #pragma unroll
    for (int i = 0; i < 4; i++) { m_i[i] = -__builtin_inff(); l_i[i] = 0.0f; }
    #pragma unroll
    for (int dt = 0; dt < 4; dt++)
        #pragma unroll
        for (int i = 0; i < 4; i++) oacc[dt][i] = 0.0f;
    __syncthreads();

    // swizzled BD row group for this wave's 16 q rows: tg = t>>2
    const int tg = (q0 >> 2) + wave * 4 + quad;

    for (int st = 0; st < 4; st++) {
        #pragma unroll
        for (int it = 0; it < 4; it++) {
            int c = it * 256 + tid, r = c >> 3, c8 = c & 7;
            *(uint4*)&Ks[r][c8 * 8] =
                *(const uint4*)(kb + ((size_t)n * T + st * 128 + r) * HD + c8 * 8);
        }
        #pragma unroll
        for (int it = 0; it < 4; it++) {
            int c = it * 256 + tid, d = c >> 4, s8 = c & 15;
            *(uint4*)&Vs[d][s8 * 8] =
                *(const uint4*)(vtb + ((size_t)n * HD + d) * T + st * 128 + s8 * 8);
        }
        __syncthreads();

        f32x4 sacc[8];
        #pragma unroll
        for (int ct = 0; ct < 8; ct++)
            #pragma unroll
            for (int i = 0; i < 4; i++) sacc[ct][i] = 0.0f;
        #pragma unroll
        for (int ks = 0; ks < 2; ks++) {
            short8 af = *(const short8*)&Qs[wave * 16 + m16][ks * 32 + quad * 8];
            #pragma unroll
            for (int ct = 0; ct < 8; ct++) {
                short8 bfr = *(const short8*)&Ks[ct * 16 + m16][ks * 32 + quad * 8];
                sacc[ct] = __builtin_amdgcn_mfma_f32_16x16x32_bf16(af, bfr, sacc[ct], 0, 0, 0);
            }
        }

        // epilogue: val = qk * D + B  (swizzled BD: one uint4 per ct)
        const bf16x2* bdst = BD + (((size_t)(n * 4 + st) * 128 + tg) * 512);
        float val[8][4];
        #pragma unroll
        for (int ct = 0; ct < 8; ct++) {
            uint4 raw = *(const uint4*)(bdst + (ct * 16 + m16) * 4);
            const bf16x2* bd = (const bf16x2*)&raw;
            #pragma unroll
            for (int i = 0; i < 4; i++)
                val[ct][i] = sacc[ct][i] * __bfloat162float(bd[i].y)
                           + __bfloat162float(bd[i].x);
        }

        float alpha[4], mn[4];
        #pragma unroll
        for (int i = 0; i < 4; i++) {
            float rm = val[0][i];
            #pragma unroll
            for (int ct = 1; ct < 8; ct++) rm = fmaxf(rm, val[ct][i]);
            #pragma unroll
            for (int o = 8; o > 0; o >>= 1) rm = fmaxf(rm, __shfl_xor(rm, o));
            mn[i] = fmaxf(m_i[i], rm);
            alpha[i] = __expf(m_i[i] - mn[i]);
            m_i[i] = mn[i];
        }
        float rs[4] = {0.0f, 0.0f, 0.0f, 0.0f};
        #pragma unroll
        for (int ct = 0; ct < 8; ct++) {
            #pragma unroll
            for (int i = 0; i < 4; i++) {
                float pv = __expf(val[ct][i] - mn[i]);
                rs[i] += pv;
                Ps[wave][quad * 4 + i][ct * 16 + m16] = __float2bfloat16(pv);
            }
        }
        #pragma unroll
        for (int i = 0; i < 4; i++) {
            #pragma unroll
            for (int o = 8; o > 0; o >>= 1) rs[i] += __shfl_xor(rs[i], o);
            l_i[i] = l_i[i] * alpha[i] + rs[i];
        }
        #pragma unroll
        for (int dt = 0; dt < 4; dt++)
            #pragma unroll
            for (int i = 0; i < 4; i++) oacc[dt][i] *= alpha[i];

        #pragma unroll
        for (int ks = 0; ks < 4; ks++) {
            short8 af = *(const short8*)&Ps[wave][m16][ks * 32 + quad * 8];
            #pragma unroll
            for (int dt = 0; dt < 4; dt++) {
                short8 bfr = *(const short8*)&Vs[dt * 16 + m16][ks * 32 + quad * 8];
                oacc[dt] = __builtin_amdgcn_mfma_f32_16x16x32_bf16(af, bfr, oacc[dt], 0, 0, 0);
            }
        }
        __syncthreads();
    }

    const int b = n / NH, hh = n % NH;
    #pragma unroll
    for (int i = 0; i < 4; i++) {
        int t = q0 + wave * 16 + quad * 4 + i;
        float inv = 1.0f / l_i[i];
        #pragma unroll
        for (int dt = 0; dt < 4; dt++) {
            int d = dt * 16 + m16;
            ab[((size_t)(t * BB + b)) * H + hh * HD + d] =
                __float2bfloat16(oacc[dt][i] * inv);
        }
    }
}

// ---------------- attn out proj + residual, split-K=2, atomic epilogue --
__global__ __launch_bounds__(256, 2) void k_out(
    const bf16* __restrict__ ab, const bf16* __restrict__ Wot,
    const float* __restrict__ bo, float* __restrict__ x)
{
    const int bm = blockIdx.x, bn = blockIdx.y, kc = blockIdx.z;
    f32x4 acc[4][4];
    for (int a = 0; a < 4; a++) for (int bb = 0; bb < 4; bb++)
        for (int i = 0; i < 4; i++) acc[a][bb][i] = 0.0f;
    gemm_core<4>(ab + (size_t)bm * 128 * H + kc * 384, H,
                 Wot + (size_t)bn * 128 * H + kc * 384, H, 384, acc);
    EPI_IDX();
    #pragma unroll
    for (int mt = 0; mt < 4; mt++)
        #pragma unroll
        for (int nt = 0; nt < 4; nt++)
            #pragma unroll
            for (int i = 0; i < 4; i++) {
                int r = bm * 128 + wr * 64 + mt * 16 + quad * 4 + i;
                int c = bn * 128 + wc * 64 + nt * 16 + m16;
                size_t idx = (size_t)r * H + c;
                float v = acc[mt][nt][i] + (kc == 0 ? bo[c] : 0.0f);
                atomicAdd(&x[idx], v);
            }
}

// ---------------- FFN1 + gelu -------------------------------------------
__global__ __launch_bounds__(256, 2) void k_ffn1(
    const bf16* __restrict__ h, const bf16* __restrict__ W1t,
    const float* __restrict__ b1, bf16* __restrict__ gb)
{
    const int bm = blockIdx.x, bn = blockIdx.y;
    f32x4 acc[4][4];
    for (int a = 0; a < 4; a++) for (int bb = 0; bb < 4; bb++)
        for (int i = 0; i < 4; i++) acc[a][bb][i] = 0.0f;
    gemm_core<4>(h + (size_t)bm * 128 * H, H, W1t + (size_t)bn * 128 * H, H, H, acc);
    EPI_IDX();
    #pragma unroll
    for (int mt = 0; mt < 4; mt++)
        #pragma unroll
        for (int nt = 0; nt < 4; nt++)
            #pragma unroll
            for (int i = 0; i < 4; i++) {
                int r = bm * 128 + wr * 64 + mt * 16 + quad * 4 + i;
                int c = bn * 128 + wc * 64 + nt * 16 + m16;
                float u = acc[mt][nt][i] + b1[c];
                float gl = 0.5f * u * (1.0f + tanhf(0.7978845608028654f * (u + 0.044715f * u * u * u)));
                gb[(size_t)r * FF + c] = __float2bfloat16(gl);
            }
}

// ---------------- FFN2 + residual, split-K=4, atomic epilogue -----------
__global__ __launch_bounds__(256, 2) void k_ffn2(
    const bf16* __restrict__ gb, const bf16* __restrict__ W2t,
    const float* __restrict__ b2, float* __restrict__ x)
{
    const int bm = blockIdx.x, bn = blockIdx.y, kc = blockIdx.z;
    f32x4 acc[4][4];
    for (int a = 0; a < 4; a++) for (int bb = 0; bb < 4; bb++)
        for (int i = 0; i < 4; i++) acc[a][bb][i] = 0.0f;
    gemm_core<4>(gb + (size_t)bm * 128 * FF + kc * 768, FF,
                 W2t + (size_t)bn * 128 * FF + kc * 768, FF, 768, acc);
    EPI_IDX();
    #pragma unroll
    for (int mt = 0; mt < 4; mt++)
        #pragma unroll
        for (int nt = 0; nt < 4; nt++)
            #pragma unroll
            for (int i = 0; i < 4; i++) {
                int r = bm * 128 + wr * 64 + mt * 16 + quad * 4 + i;
                int c = bn * 128 + wc * 64 + nt * 16 + m16;
                size_t idx = (size_t)r * H + c;
                float v = acc[mt][nt][i] + (kc == 0 ? b2[c] : 0.0f);
                atomicAdd(&x[idx], v);
            }
}

// ---------------- host ---------------------------------------------------
extern "C" void kernel_launch(void* const* d_in, const int* in_sizes, int n_in,
                              void* d_out, int out_size, void* d_ws, size_t ws_size,
                              hipStream_t stream) {
    const float* x_in  = (const float*)d_in[0];
    const float* abias = (const float*)d_in[1];
    const float* decay = (const float*)d_in[2];
    const int*   am    = (const int*)d_in[3];
    const float* Wq = (const float*)d_in[4];
    const float* bq = (const float*)d_in[5];
    const float* Wk = (const float*)d_in[6];
    const float* bk = (const float*)d_in[7];
    const float* Wv = (const float*)d_in[8];
    const float* bv = (const float*)d_in[9];
    const float* Wo = (const float*)d_in[10];
    const float* bo = (const float*)d_in[11];
    const float* ln1g = (const float*)d_in[12];
    const float* ln1b = (const float*)d_in[13];
    const float* ln2g = (const float*)d_in[14];
    const float* ln2b = (const float*)d_in[15];
    const float* W1 = (const float*)d_in[16];
    const float* b1 = (const float*)d_in[17];
    const float* W2 = (const float*)d_in[18];
    const float* b2 = (const float*)d_in[19];
    float* x = (float*)d_out;

    char* p = (char*)d_ws;
    auto alloc = [&](size_t bytes) {
        char* r = p;
        p += (bytes + 255) & ~(size_t)255;
        return r;
    };
    bf16* Wqt = (bf16*)alloc((size_t)LYR * H * H * 2);
    bf16* Wkt = (bf16*)alloc((size_t)LYR * H * H * 2);
    bf16* Wvt = (bf16*)alloc((size_t)LYR * H * H * 2);
    bf16* Wot = (bf16*)alloc((size_t)LYR * H * H * 2);
    bf16* W1t = (bf16*)alloc((size_t)LYR * H * FF * 2);
    bf16* W2t = (bf16*)alloc((size_t)LYR * H * FF * 2);
    bf16* hbuf = (bf16*)alloc((size_t)M_TOK * H * 2);
    bf16* qb   = (bf16*)alloc((size_t)BB * NH * T * HD * 2);
    bf16* kb   = (bf16*)alloc((size_t)BB * NH * T * HD * 2);
    bf16* vtb  = (bf16*)alloc((size_t)BB * NH * T * HD * 2);
    bf16* ab   = (bf16*)alloc((size_t)BB * NH * T * HD * 2);
    bf16x2* BD = (bf16x2*)alloc((size_t)BB * NH * T * T * 4);
    bf16* gb   = (bf16*)alloc((size_t)M_TOK * FF * 2);

    hipMemcpyAsync(x, x_in, (size_t)M_TOK * H * 4, hipMemcpyDeviceToDevice, stream);

    dim3 blk(256);
    k_prep<<<dim3(T / 16, 4, BB * NH), blk, 0, stream>>>(abias, decay, am, BD);
    k_transpose<<<dim3(H / 64, H / 64, LYR), blk, 0, stream>>>(Wq, Wqt, H, H);
    k_transpose<<<dim3(H / 64, H / 64, LYR), blk, 0, stream>>>(Wk, Wkt, H, H);
    k_transpose<<<dim3(H / 64, H / 64, LYR), blk, 0, stream>>>(Wv, Wvt, H, H);
    k_transpose<<<dim3(H / 64, H / 64, LYR), blk, 0, stream>>>(Wo, Wot, H, H);
    k_transpose<<<dim3(FF / 64, H / 64, LYR), blk, 0, stream>>>(W1, W1t, H, FF);
    k_transpose<<<dim3(H / 64, FF / 64, LYR), blk, 0, stream>>>(W2, W2t, FF, H);

    for (int l = 0; l < LYR; l++) {
        size_t wo = (size_t)l * H * H;
        size_t wf = (size_t)l * H * FF;
        k_ln<<<dim3(M_TOK), blk, 0, stream>>>(x, ln1g + l * H, ln1b + l * H, hbuf);
        k_qkv<<<dim3(16, 18), blk, 0, stream>>>(hbuf, Wqt + wo, Wkt + wo, Wvt + wo,
                                                bq + l * H, bk + l * H, bv + l * H,
                                                qb, kb, vtb);
        k_attn<<<dim3(T / 64, BB * NH), blk, 0, stream>>>(qb, kb, vtb, BD, ab);
        k_out<<<dim3(16, 6, 2), blk, 0, stream>>>(ab, Wot + wo, bo + l * H, x);
        k_ln<<<dim3(M_TOK), blk, 0, stream>>>(x, ln2g + l * H, ln2b + l * H, hbuf);
        k_ffn1<<<dim3(16, 24), blk, 0, stream>>>(hbuf, W1t + wf, b1 + l * FF, gb);
        k_ffn2<<<dim3(16, 6, 4), blk, 0, stream>>>(gb, W2t + wf, b2 + l * H, x);
    }
}